// Round 1
// baseline (526.184 us; speedup 1.0000x reference)
//
#include <hip/hip_runtime.h>

typedef unsigned short u16;
typedef unsigned int u32;
typedef __attribute__((ext_vector_type(8))) __bf16 bf16x8;
typedef __attribute__((ext_vector_type(4))) float f32x4;
typedef __attribute__((ext_vector_type(4))) short s16x4;

#define LOG2E 1.4426950408889634f
#define NINF (-__builtin_inff())

// ---------------- workspace layout (u16 element offsets) ----------------
// W^T (bf16) for all projections, then staging buffers.
static constexpr size_t OFF_WT_CKV = 0;          // 256x1024
static constexpr size_t OFF_WT_CQ  = 262144;     // 256x1024
static constexpr size_t OFF_WT_KC  = 524288;     // 1024x256
static constexpr size_t OFF_WT_QC  = 786432;     // 1024x256
static constexpr size_t OFF_WT_VC  = 1048576;    // 1024x256
static constexpr size_t OFF_WT_PROJ= 1310720;    // 1024x1024
static constexpr size_t OFF_XBF    = 2359296;    // 4096x1024 bf16 x  (reused as CTX)
static constexpr size_t OFF_DQ     = OFF_XBF + 4194304;  // 4096x512 [KV | Qdown]
static constexpr size_t OFF_KB     = OFF_DQ  + 2097152;  // (b,h,t,d) 4M
static constexpr size_t OFF_QB     = OFF_KB  + 4194304;  // (b,h,t,d), pre-scaled by 1/8
static constexpr size_t OFF_VTB    = OFF_QB  + 4194304;  // (b,h,d,t)
static constexpr size_t OFF_CTX    = OFF_XBF;            // alias: x dead after K1
// total = 21233664 elems = 42.5 MB

__device__ __forceinline__ u16 f2bf(float f) {   // RNE fp32->bf16
  u32 u = __builtin_bit_cast(u32, f);
  u = (u + 0x7fffu + ((u >> 16) & 1u)) >> 16;
  return (u16)u;
}

// async global->LDS, 16B per lane. LDS dest = wave-uniform base + lane*16.
__device__ __forceinline__ void gld16(const void* g, void* l) {
  __builtin_amdgcn_global_load_lds(
      (const __attribute__((address_space(1))) u32*)(unsigned long long)g,
      (__attribute__((address_space(3))) u32*)(u32)(unsigned long long)l,
      16, 0, 0);
}

// ---------------- K0: convert x -> bf16, W -> bf16 transposed ----------------
__global__ __launch_bounds__(256) void convert_kernel(
    const float* __restrict__ xin, const float* __restrict__ w0,
    const float* __restrict__ w1, const float* __restrict__ w2,
    const float* __restrict__ w3, const float* __restrict__ w4,
    const float* __restrict__ w5, u16* __restrict__ ws) {
  int id = blockIdx.x * 256 + threadIdx.x;
  if (id < 4194304) { ws[OFF_XBF + id] = f2bf(xin[id]); return; }
  id -= 4194304;
  if (id < 262144) { int k = id >> 8, n = id & 255;
    ws[OFF_WT_CKV + (size_t)n*1024 + k] = f2bf(w0[id]); return; }
  id -= 262144;
  if (id < 262144) { int k = id >> 8, n = id & 255;
    ws[OFF_WT_CQ + (size_t)n*1024 + k] = f2bf(w1[id]); return; }
  id -= 262144;
  if (id < 262144) { int k = id >> 10, n = id & 1023;
    ws[OFF_WT_KC + (size_t)n*256 + k] = f2bf(w2[id]); return; }
  id -= 262144;
  if (id < 262144) { int k = id >> 10, n = id & 1023;
    ws[OFF_WT_QC + (size_t)n*256 + k] = f2bf(w3[id]); return; }
  id -= 262144;
  if (id < 262144) { int k = id >> 10, n = id & 1023;
    ws[OFF_WT_VC + (size_t)n*256 + k] = f2bf(w4[id]); return; }
  id -= 262144;
  if (id < 1048576) { int k = id >> 10, n = id & 1023;
    ws[OFF_WT_PROJ + (size_t)n*1024 + k] = f2bf(w5[id]); return; }
}

// ---------------- m97-style GEMM: C(4096 x N) = A(4096 x K) * BT^T ----------------
// MODE 0: K1  A=XBF lda=1024, K=1024, N=512 -> DQ bf16 (ldc=512)
// MODE 1: K2  A=DQ  lda=512,  K=256,  N=3072 -> K/(Q*0.125)/V^T  (bhtd / bhdt)
// MODE 2: K4  A=CTX lda=1024, K=1024, N=1024 -> d_out fp32 + bias
template<int MODE>
__global__ __launch_bounds__(256, 2) void gemm_kernel(
    const u16* __restrict__ A, const u16* __restrict__ BT,
    u16* __restrict__ ws, float* __restrict__ out, const float* __restrict__ bias) {
  constexpr int KDIM = (MODE == 1) ? 256 : 1024;
  constexpr int LDA  = (MODE == 1) ? 512 : 1024;
  __shared__ u16 lA[128*32];
  __shared__ u16 lB[128*32];
  const int t = threadIdx.x;
  const int lane = t & 63;
  const int c = lane & 15, quad = lane >> 4;
  const int w = t >> 6, wr = w >> 1, wc = w & 1;
  const int gm0 = blockIdx.y * 128, ct0 = blockIdx.x * 128;
  const u16* Ae = A;
  int out_id = 0;
  if (MODE == 1) { out_id = ct0 >> 10; if (out_id == 1) Ae += 256; }
  const int m0s = t >> 2, q0s = t & 3;     // staging slot decode (slot = m*4+q, 16B each)
  const int m1s = m0s + 64;

  f32x4 acc[4][4];
  #pragma unroll
  for (int i = 0; i < 4; ++i)
    #pragma unroll
    for (int j = 0; j < 4; ++j) acc[i][j] = (f32x4)0.0f;

  for (int k0 = 0; k0 < KDIM; k0 += 32) {
    __syncthreads();   // prior frag reads drained (compiler waits before s_barrier)
    gld16(Ae + (size_t)(gm0 + m0s)*LDA + k0 + q0s*8, (char*)lA + t*16);
    gld16(Ae + (size_t)(gm0 + m1s)*LDA + k0 + q0s*8, (char*)lA + (t+256)*16);
    gld16(BT + (size_t)(ct0 + m0s)*KDIM + k0 + q0s*8, (char*)lB + t*16);
    gld16(BT + (size_t)(ct0 + m1s)*KDIM + k0 + q0s*8, (char*)lB + (t+256)*16);
    __syncthreads();
    bf16x8 af[4], bfr[4];
    #pragma unroll
    for (int mt = 0; mt < 4; ++mt)
      af[mt] = *(const bf16x8*)(lA + (wr*64 + mt*16 + c)*32 + quad*8);
    #pragma unroll
    for (int nt = 0; nt < 4; ++nt)
      bfr[nt] = *(const bf16x8*)(lB + (wc*64 + nt*16 + c)*32 + quad*8);
    #pragma unroll
    for (int mt = 0; mt < 4; ++mt)
      #pragma unroll
      for (int nt = 0; nt < 4; ++nt)
        acc[mt][nt] = __builtin_amdgcn_mfma_f32_16x16x32_bf16(af[mt], bfr[nt], acc[mt][nt], 0, 0, 0);
  }

  const int rbase = gm0 + wr*64;
  const int cbase = ct0 + wc*64;
  if (MODE == 0) {
    #pragma unroll
    for (int mt = 0; mt < 4; ++mt)
      #pragma unroll
      for (int nt = 0; nt < 4; ++nt)
        #pragma unroll
        for (int j = 0; j < 4; ++j) {
          int row = rbase + mt*16 + quad*4 + j;
          int col = cbase + nt*16 + c;
          ws[OFF_DQ + (size_t)row*512 + col] = f2bf(acc[mt][nt][j]);
        }
  } else if (MODE == 2) {
    float bv[4];
    #pragma unroll
    for (int nt = 0; nt < 4; ++nt) bv[nt] = bias[cbase + nt*16 + c];
    #pragma unroll
    for (int mt = 0; mt < 4; ++mt)
      #pragma unroll
      for (int nt = 0; nt < 4; ++nt)
        #pragma unroll
        for (int j = 0; j < 4; ++j) {
          int row = rbase + mt*16 + quad*4 + j;
          out[(size_t)row*1024 + cbase + nt*16 + c] = acc[mt][nt][j] + bv[nt];
        }
  } else {
    const int cl = (ct0 & 1023) + wc*64;
    const int hcol = cl >> 6;                 // head for this wave-col (d = nt*16+c)
    if (out_id == 2) {                        // V -> (b,h,d,t), pack 4 consecutive t
      #pragma unroll
      for (int mt = 0; mt < 4; ++mt) {
        int row0 = rbase + mt*16 + quad*4;
        int bb = row0 >> 10, t0 = row0 & 1023;
        #pragma unroll
        for (int nt = 0; nt < 4; ++nt) {
          int d = nt*16 + c;
          s16x4 pk;
          #pragma unroll
          for (int j = 0; j < 4; ++j) pk[j] = (short)f2bf(acc[mt][nt][j]);
          *(s16x4*)(ws + OFF_VTB + (((size_t)bb*16 + hcol)*64 + d)*1024 + t0) = pk;
        }
      }
    } else {                                  // K / Q(*1/8) -> (b,h,t,d)
      const float sc = out_id ? 0.125f : 1.0f;  // power of 2: exact in bf16
      const size_t base = out_id ? OFF_QB : OFF_KB;
      #pragma unroll
      for (int mt = 0; mt < 4; ++mt)
        #pragma unroll
        for (int nt = 0; nt < 4; ++nt)
          #pragma unroll
          for (int j = 0; j < 4; ++j) {
            int row = rbase + mt*16 + quad*4 + j;
            int bb = row >> 10, tt = row & 1023;
            ws[base + ((((size_t)bb*16 + hcol)*1024 + tt)<<6) + nt*16 + c]
                = f2bf(acc[mt][nt][j]*sc);
          }
    }
  }
}

// ---------------- K3: flash attention with fused interaction-matrix add ----------------
// block = 512 thr = 8 waves = 8 heads (h0 or h0+8 half); q-tile = 16 rows; k-tile = 32.
// grid swizzle: XCD = bi&7 -> b=(bi&7)>>1 (K/V/Q of one b pinned to 2 XCDs' L2);
// h-sibling blocks 8 apart (same XCD -> IM 64B lines shared); qt descending (long first).
__global__ __launch_bounds__(512, 4) void attn_kernel(
    const u16* __restrict__ Kb, const u16* __restrict__ Qb,
    const u16* __restrict__ VTb, u16* __restrict__ ctx,
    const float* __restrict__ im, const int* __restrict__ pmask) {
  __shared__ float lim[32*132];        // IM tile [k][q*8 + hw], row stride 132
  __shared__ u16   lp[8][16*40];       // per-wave P [q=16][key pad to 40]
  typedef __attribute__((ext_vector_type(4))) float float4v;

  const int t = threadIdx.x, lane = t & 63, w = t >> 6;
  const int c = lane & 15, quad = lane >> 4;
  const int bi = blockIdx.x;
  const int xcd = bi & 7, b = xcd >> 1, p0 = xcd & 1;
  const int hh = (bi >> 3) & 1, hi = bi >> 4;
  const int qt = 63 - ((hi << 1) | p0);
  const int h0 = hh * 8, h = h0 + w;
  const int qmax = qt*16 + 15;
  const int ktmax = qmax >> 5;
  const size_t bh = ((size_t)b*16 + h) << 16;   // *(1024*64)

  // Q A-frags (m = lane&15 -> q-row, k = quad*8+j -> d), scale 1/8 already folded
  bf16x8 qf0 = *(const bf16x8*)(Qb + bh + (size_t)(qt*16 + c)*64 + quad*8);
  bf16x8 qf1 = *(const bf16x8*)(Qb + bh + (size_t)(qt*16 + c)*64 + 32 + quad*8);

  int tq[4], rm[4];
  #pragma unroll
  for (int j = 0; j < 4; ++j) {
    tq[j] = qt*16 + quad*4 + j;
    rm[j] = pmask[b*1024 + tq[j]];
  }
  float mr[4] = {NINF, NINF, NINF, NINF};
  float lr[4] = {0.f, 0.f, 0.f, 0.f};
  f32x4 O[4] = {(f32x4)0.f, (f32x4)0.f, (f32x4)0.f, (f32x4)0.f};

  for (int kt = 0; kt <= ktmax; ++kt) {
    const int kb = kt*32;
    const int nk = min(32, qmax + 1 - kb);
    __syncthreads();
    // stage IM[b, kb+k, qt*16+q, h0..h0+7] -> LDS (stream-once: nontemporal)
    #pragma unroll
    for (int i = 0; i < 2; ++i) {
      int s = i*512 + t;                      // 1024 float4 chunks
      int k = s >> 5, sub = s & 31, q = sub >> 1, hp = (sub & 1)*4;
      if (k < nk) {
        float4v v = __builtin_nontemporal_load((const float4v*)(
            im + (((size_t)b*1024 + kb + k)*1024 + qt*16 + q)*16 + h0 + hp));
        *(float4v*)(lim + k*132 + q*8 + hp) = v;
      }
    }
    __syncthreads();

    // S = Q*K^T  (16 q x 32 keys)
    f32x4 S[2] = {(f32x4)0.f, (f32x4)0.f};
    #pragma unroll
    for (int nt = 0; nt < 2; ++nt) {
      const u16* kp = Kb + bh + (size_t)(kb + nt*16 + c)*64 + quad*8;
      bf16x8 kf0 = *(const bf16x8*)kp;
      bf16x8 kf1 = *(const bf16x8*)(kp + 32);
      S[nt] = __builtin_amdgcn_mfma_f32_16x16x32_bf16(qf0, kf0, S[nt], 0, 0, 0);
      S[nt] = __builtin_amdgcn_mfma_f32_16x16x32_bf16(qf1, kf1, S[nt], 0, 0, 0);
    }
    // add IM, padding-mask (masked q-row: -1e9+IM == -1e9 in fp32 -> uniform == const 0),
    // causal
    #pragma unroll
    for (int nt = 0; nt < 2; ++nt) {
      int tk = kb + nt*16 + c;
      #pragma unroll
      for (int j = 0; j < 4; ++j) {
        float s = S[nt][j] + lim[(nt*16 + c)*132 + (quad*4 + j)*8 + w];
        s = rm[j] ? s : 0.0f;
        s = (tk <= tq[j]) ? s : NINF;
        S[nt][j] = s;
      }
    }
    // online softmax (rows live on (quad,j); reduce across the 16 c-lanes)
    float mn[4], al[4];
    #pragma unroll
    for (int j = 0; j < 4; ++j) {
      float vm = fmaxf(S[0][j], S[1][j]);
      vm = fmaxf(vm, __shfl_xor(vm, 1, 64));
      vm = fmaxf(vm, __shfl_xor(vm, 2, 64));
      vm = fmaxf(vm, __shfl_xor(vm, 4, 64));
      vm = fmaxf(vm, __shfl_xor(vm, 8, 64));
      mn[j] = fmaxf(mr[j], vm);
      al[j] = exp2f((mr[j] - mn[j]) * LOG2E);
      mr[j] = mn[j];
    }
    float p[2][4];
    #pragma unroll
    for (int nt = 0; nt < 2; ++nt)
      #pragma unroll
      for (int j = 0; j < 4; ++j)
        p[nt][j] = exp2f((S[nt][j] - mn[j]) * LOG2E);
    #pragma unroll
    for (int j = 0; j < 4; ++j) {
      float sum = p[0][j] + p[1][j];
      sum += __shfl_xor(sum, 1, 64);
      sum += __shfl_xor(sum, 2, 64);
      sum += __shfl_xor(sum, 4, 64);
      sum += __shfl_xor(sum, 8, 64);
      lr[j] = lr[j]*al[j] + sum;
    }
    #pragma unroll
    for (int nd = 0; nd < 4; ++nd)
      #pragma unroll
      for (int j = 0; j < 4; ++j) O[nd][j] *= al[j];
    // P: C-layout -> A-layout via private LDS (same-wave DS ops are ordered)
    #pragma unroll
    for (int nt = 0; nt < 2; ++nt)
      #pragma unroll
      for (int j = 0; j < 4; ++j)
        lp[w][(quad*4 + j)*40 + nt*16 + c] = f2bf(p[nt][j]);
    bf16x8 pf = *(const bf16x8*)&lp[w][c*40 + quad*8];
    // O += P*V   (V^T layout: 8 contiguous keys per frag)
    #pragma unroll
    for (int nd = 0; nd < 4; ++nd) {
      bf16x8 vf = *(const bf16x8*)(VTb + bh + (size_t)(nd*16 + c)*1024 + kb + quad*8);
      O[nd] = __builtin_amdgcn_mfma_f32_16x16x32_bf16(pf, vf, O[nd], 0, 0, 0);
    }
  }

  float inv[4];
  #pragma unroll
  for (int j = 0; j < 4; ++j) inv[j] = 1.0f / lr[j];
  #pragma unroll
  for (int nd = 0; nd < 4; ++nd)
    #pragma unroll
    for (int j = 0; j < 4; ++j)
      ctx[((size_t)b*1024 + tq[j])*1024 + h*64 + nd*16 + c] = f2bf(O[nd][j] * inv[j]);
}

// ---------------- launch ----------------
extern "C" void kernel_launch(void* const* d_in, const int* in_sizes, int n_in,
                              void* d_out, int out_size, void* d_ws, size_t ws_size,
                              hipStream_t stream) {
  const float* x     = (const float*)d_in[0];
  const int*   pm    = (const int*)d_in[1];
  const float* im    = (const float*)d_in[2];
  const float* wckv  = (const float*)d_in[3];
  const float* wcq   = (const float*)d_in[4];
  const float* wkc   = (const float*)d_in[5];
  const float* wqc   = (const float*)d_in[6];
  const float* wvc   = (const float*)d_in[7];
  const float* wproj = (const float*)d_in[8];
  const float* bproj = (const float*)d_in[9];
  u16* ws = (u16*)d_ws;
  float* out = (float*)d_out;

  convert_kernel<<<25600, 256, 0, stream>>>(x, wckv, wcq, wkc, wqc, wvc, wproj, ws);
  // K1: [KV|Qd] = Xbf @ [W_ckv|W_cq]   (4096x512, K=1024)
  gemm_kernel<0><<<dim3(4, 32), 256, 0, stream>>>(ws + OFF_XBF, ws + OFF_WT_CKV, ws, nullptr, nullptr);
  // K2: K / Q*(1/8) / V^T   (4096x3072, K=256)
  gemm_kernel<1><<<dim3(24, 32), 256, 0, stream>>>(ws + OFF_DQ, ws + OFF_WT_KC, ws, nullptr, nullptr);
  // K3: flash attention + interaction matrix
  attn_kernel<<<512, 512, 0, stream>>>(ws + OFF_KB, ws + OFF_QB, ws + OFF_VTB,
                                       ws + OFF_CTX, im, pm);
  // K4: out = CTX @ W_proj + b_proj  (fp32)
  gemm_kernel<2><<<dim3(8, 32), 256, 0, stream>>>(ws + OFF_CTX, ws + OFF_WT_PROJ, ws, out, bproj);
}

// Round 2
// 477.218 us; speedup vs baseline: 1.1026x; 1.1026x over previous
//
#include <hip/hip_runtime.h>

typedef unsigned short u16;
typedef unsigned int u32;
typedef __attribute__((ext_vector_type(8))) __bf16 bf16x8;
typedef __attribute__((ext_vector_type(4))) float f32x4;
typedef __attribute__((ext_vector_type(4))) short s16x4;
typedef __attribute__((ext_vector_type(4))) u32 u32x4;

#define LOG2E 1.4426950408889634f
#define NINF (-__builtin_inff())

// ---------------- workspace layout (u16 element offsets) ----------------
static constexpr size_t OFF_WT_CKV = 0;          // 256x1024
static constexpr size_t OFF_WT_CQ  = 262144;     // 256x1024
static constexpr size_t OFF_WT_KC  = 524288;     // 1024x256
static constexpr size_t OFF_WT_QC  = 786432;     // 1024x256
static constexpr size_t OFF_WT_VC  = 1048576;    // 1024x256
static constexpr size_t OFF_WT_PROJ= 1310720;    // 1024x1024
static constexpr size_t OFF_XBF    = 2359296;    // 4096x1024 bf16 x  (reused as CTX)
static constexpr size_t OFF_DQ     = OFF_XBF + 4194304;  // 4096x512 [KV | Qdown]
static constexpr size_t OFF_KB     = OFF_DQ  + 2097152;  // (b,h,t,d)
static constexpr size_t OFF_QB     = OFF_KB  + 4194304;  // (b,h,t,d), pre-scaled by 1/8
static constexpr size_t OFF_VTB    = OFF_QB  + 4194304;  // (b,h,d,t)
static constexpr size_t OFF_CTX    = OFF_XBF;            // alias: x dead after K1

__device__ __forceinline__ u16 f2bf(float f) {   // RNE fp32->bf16
  u32 u = __builtin_bit_cast(u32, f);
  u = (u + 0x7fffu + ((u >> 16) & 1u)) >> 16;
  return (u16)u;
}

// async global->LDS, 16B per lane. LDS dest = wave-uniform base + lane*16.
__device__ __forceinline__ void gld16(const void* g, void* l) {
  __builtin_amdgcn_global_load_lds(
      (const __attribute__((address_space(1))) u32*)(unsigned long long)g,
      (__attribute__((address_space(3))) u32*)(u32)(unsigned long long)l,
      16, 0, 0);
}

// ---------------- K0: convert x -> bf16 (x8 vectorized), W -> bf16 transposed ----------------
__global__ __launch_bounds__(256) void convert_kernel(
    const float* __restrict__ xin, const float* __restrict__ w0,
    const float* __restrict__ w1, const float* __restrict__ w2,
    const float* __restrict__ w3, const float* __restrict__ w4,
    const float* __restrict__ w5, u16* __restrict__ ws) {
  int gid = blockIdx.x * 256 + threadIdx.x;
  if (gid < 524288) {                          // x: 8 elems/thread, fully vectorized
    int i0 = gid * 8;
    f32x4 a = *(const f32x4*)(xin + i0);
    f32x4 b = *(const f32x4*)(xin + i0 + 4);
    u32x4 pv;
    pv[0] = (u32)f2bf(a[0]) | ((u32)f2bf(a[1]) << 16);
    pv[1] = (u32)f2bf(a[2]) | ((u32)f2bf(a[3]) << 16);
    pv[2] = (u32)f2bf(b[0]) | ((u32)f2bf(b[1]) << 16);
    pv[3] = (u32)f2bf(b[2]) | ((u32)f2bf(b[3]) << 16);
    *(u32x4*)(ws + OFF_XBF + i0) = pv;
    return;
  }
  int id = gid - 524288;
  if (id < 262144) { int k = id >> 8, n = id & 255;
    ws[OFF_WT_CKV + (size_t)n*1024 + k] = f2bf(w0[id]); return; }
  id -= 262144;
  if (id < 262144) { int k = id >> 8, n = id & 255;
    ws[OFF_WT_CQ + (size_t)n*1024 + k] = f2bf(w1[id]); return; }
  id -= 262144;
  if (id < 262144) { int k = id >> 10, n = id & 1023;
    ws[OFF_WT_KC + (size_t)n*256 + k] = f2bf(w2[id]); return; }
  id -= 262144;
  if (id < 262144) { int k = id >> 10, n = id & 1023;
    ws[OFF_WT_QC + (size_t)n*256 + k] = f2bf(w3[id]); return; }
  id -= 262144;
  if (id < 262144) { int k = id >> 10, n = id & 1023;
    ws[OFF_WT_VC + (size_t)n*256 + k] = f2bf(w4[id]); return; }
  id -= 262144;
  if (id < 1048576) { int k = id >> 10, n = id & 1023;
    ws[OFF_WT_PROJ + (size_t)n*1024 + k] = f2bf(w5[id]); return; }
}

// ---------------- m97-style GEMM: C(4096 x N) = A(4096 x K) * BT^T ----------------
// MODE 0: K1  A=XBF lda=1024, K=1024, N=512 -> DQ bf16     (MT=64, NT=64,  grid 512)
// MODE 1: K2  A=DQ  lda=512,  K=256,  N=3072 -> K/Q/V^T    (MT=128,NT=128, grid 768)
// MODE 2: K4  A=CTX lda=1024, K=1024, N=1024 -> out + bias (MT=64, NT=128, grid 512)
template<int MODE, int MT, int NT>
__global__ __launch_bounds__(256, (MT == 128) ? 2 : 4) void gemm_kernel(
    const u16* __restrict__ A, const u16* __restrict__ BT,
    u16* __restrict__ ws, float* __restrict__ out, const float* __restrict__ bias) {
  constexpr int KDIM = (MODE == 1) ? 256 : 1024;
  constexpr int LDA  = (MODE == 1) ? 512 : 1024;
  constexpr int MW = MT / 32;   // m-frags per wave
  constexpr int NW = NT / 32;   // n-frags per wave
  __shared__ u16 lA[MT*32];
  __shared__ u16 lB[NT*32];
  const int t = threadIdx.x;
  const int lane = t & 63;
  const int c = lane & 15, quad = lane >> 4;
  const int w = t >> 6, wr = w >> 1, wc = w & 1;
  const int gm0 = blockIdx.y * MT, ct0 = blockIdx.x * NT;
  const u16* Ae = A;
  int out_id = 0;
  if (MODE == 1) { out_id = ct0 >> 10; if (out_id == 1) Ae += 256; }
  const int m0s = t >> 2, q0s = t & 3;

  f32x4 acc[MW][NW];
  #pragma unroll
  for (int i = 0; i < MW; ++i)
    #pragma unroll
    for (int j = 0; j < NW; ++j) acc[i][j] = (f32x4)0.0f;

  for (int k0 = 0; k0 < KDIM; k0 += 32) {
    __syncthreads();
    gld16(Ae + (size_t)(gm0 + m0s)*LDA + k0 + q0s*8, (char*)lA + t*16);
    if (MT == 128)
      gld16(Ae + (size_t)(gm0 + m0s + 64)*LDA + k0 + q0s*8, (char*)lA + (t+256)*16);
    gld16(BT + (size_t)(ct0 + m0s)*KDIM + k0 + q0s*8, (char*)lB + t*16);
    if (NT == 128)
      gld16(BT + (size_t)(ct0 + m0s + 64)*KDIM + k0 + q0s*8, (char*)lB + (t+256)*16);
    __syncthreads();
    bf16x8 af[MW], bfr[NW];
    #pragma unroll
    for (int mt = 0; mt < MW; ++mt)
      af[mt] = *(const bf16x8*)(lA + (wr*(MT/2) + mt*16 + c)*32 + quad*8);
    #pragma unroll
    for (int nt = 0; nt < NW; ++nt)
      bfr[nt] = *(const bf16x8*)(lB + (wc*(NT/2) + nt*16 + c)*32 + quad*8);
    #pragma unroll
    for (int mt = 0; mt < MW; ++mt)
      #pragma unroll
      for (int nt = 0; nt < NW; ++nt)
        acc[mt][nt] = __builtin_amdgcn_mfma_f32_16x16x32_bf16(af[mt], bfr[nt], acc[mt][nt], 0, 0, 0);
  }

  const int rbase = gm0 + wr*(MT/2);
  const int cbase = ct0 + wc*(NT/2);
  if (MODE == 0) {
    #pragma unroll
    for (int mt = 0; mt < MW; ++mt)
      #pragma unroll
      for (int nt = 0; nt < NW; ++nt)
        #pragma unroll
        for (int j = 0; j < 4; ++j) {
          int row = rbase + mt*16 + quad*4 + j;
          int col = cbase + nt*16 + c;
          ws[OFF_DQ + (size_t)row*512 + col] = f2bf(acc[mt][nt][j]);
        }
  } else if (MODE == 2) {
    float bv[NW];
    #pragma unroll
    for (int nt = 0; nt < NW; ++nt) bv[nt] = bias[cbase + nt*16 + c];
    #pragma unroll
    for (int mt = 0; mt < MW; ++mt)
      #pragma unroll
      for (int nt = 0; nt < NW; ++nt)
        #pragma unroll
        for (int j = 0; j < 4; ++j) {
          int row = rbase + mt*16 + quad*4 + j;
          out[(size_t)row*1024 + cbase + nt*16 + c] = acc[mt][nt][j] + bv[nt];
        }
  } else {
    const int cl = (ct0 & 1023) + wc*64;
    const int hcol = cl >> 6;                 // head for this wave-col
    if (out_id == 2) {                        // V -> (b,h,d,t)
      #pragma unroll
      for (int mt = 0; mt < MW; ++mt) {
        int row0 = rbase + mt*16 + quad*4;
        int bb = row0 >> 10, t0 = row0 & 1023;
        #pragma unroll
        for (int nt = 0; nt < NW; ++nt) {
          int d = nt*16 + c;
          s16x4 pk;
          #pragma unroll
          for (int j = 0; j < 4; ++j) pk[j] = (short)f2bf(acc[mt][nt][j]);
          *(s16x4*)(ws + OFF_VTB + (((size_t)bb*16 + hcol)*64 + d)*1024 + t0) = pk;
        }
      }
    } else {                                  // K / Q(*1/8) -> (b,h,t,d)
      const float sc = out_id ? 0.125f : 1.0f;
      const size_t base = out_id ? OFF_QB : OFF_KB;
      #pragma unroll
      for (int mt = 0; mt < MW; ++mt)
        #pragma unroll
        for (int nt = 0; nt < NW; ++nt)
          #pragma unroll
          for (int j = 0; j < 4; ++j) {
            int row = rbase + mt*16 + quad*4 + j;
            int bb = row >> 10, tt = row & 1023;
            ws[base + ((((size_t)bb*16 + hcol)*1024 + tt)<<6) + nt*16 + c]
                = f2bf(acc[mt][nt][j]*sc);
          }
    }
  }
}

// ---------------- K3: flash attention + fused interaction-matrix ----------------
// 256 blocks x 512 thr; block = (b, hh, pair); does q-tiles qt=63-pair then qt=pair
// (constant 33 k-tiles/block -> perfect balance at 1 block/CU).
// bi = g*16 + hh*8 + s, s = b*2 + (pair&1): hh-siblings differ by 8 -> same XCD
// (bi%8 round-robin) -> each 64B IM line fetched once into that XCD's L2.
// IM pipeline: register double-buffer (prefetch next k-tile during compute).
// lim swizzle: k-stride 196, q-stride 12 floats -> <=4-way bank conflicts.
__global__ __launch_bounds__(512, 2) void attn_kernel(
    const u16* __restrict__ Kb, const u16* __restrict__ Qb,
    const u16* __restrict__ VTb, u16* __restrict__ ctx,
    const float* __restrict__ im, const int* __restrict__ pmask) {
  __shared__ float lim[32*196];
  __shared__ u16   lp[8][16*40];

  const int t = threadIdx.x, lane = t & 63, w = t >> 6;
  const int c = lane & 15, quad = lane >> 4;
  const int bi = blockIdx.x;
  const int g = bi >> 4, hh = (bi >> 3) & 1, s = bi & 7;
  const int b = s >> 1, pair = g*2 + (s & 1);
  const int h0 = hh*8, h = h0 + w;
  const size_t bh = ((size_t)b*16 + h) << 16;

  // staging chunk decode: chunk0 = t (k 0..15), chunk1 = t+512 (k 16..31)
  const int k0s = t >> 5, q0s = (t & 31) >> 1, hp0 = (t & 1) * 4;
  const float* imb = im + ((size_t)b << 24) + h0;   // b*1024*1024*16
  float* l0 = lim + k0s*196 + q0s*12 + hp0;
  float* l1 = lim + (k0s + 16)*196 + q0s*12 + hp0;

  const int qtA = 63 - pair;
  f32x4 r0 = *(const f32x4*)(imb + (((size_t)k0s)*1024 + qtA*16 + q0s)*16 + hp0);
  f32x4 r1 = *(const f32x4*)(imb + (((size_t)(k0s+16))*1024 + qtA*16 + q0s)*16 + hp0);

  for (int pass = 0; pass < 2; ++pass) {
    const int qt = pass ? pair : qtA;
    const int qrow0 = qt * 16;
    const int ktmax = (qrow0 + 15) >> 5;

    bf16x8 qf0 = *(const bf16x8*)(Qb + bh + (size_t)(qrow0 + c)*64 + quad*8);
    bf16x8 qf1 = *(const bf16x8*)(Qb + bh + (size_t)(qrow0 + c)*64 + 32 + quad*8);

    int tq[4], rm[4];
    #pragma unroll
    for (int j = 0; j < 4; ++j) {
      tq[j] = qrow0 + quad*4 + j;
      rm[j] = pmask[b*1024 + tq[j]];
    }
    float mr[4] = {NINF, NINF, NINF, NINF};
    float lr[4] = {0.f, 0.f, 0.f, 0.f};
    f32x4 O[4] = {(f32x4)0.f, (f32x4)0.f, (f32x4)0.f, (f32x4)0.f};

    for (int kt = 0; kt <= ktmax; ++kt) {
      const int kb = kt*32;
      __syncthreads();                 // prior tile's lim reads done (all waves)
      *(f32x4*)l0 = r0;
      *(f32x4*)l1 = r1;
      __syncthreads();
      // prefetch next IM tile (this pass, or first tile of pass B)
      if (kt < ktmax) {
        r0 = *(const f32x4*)(imb + (((size_t)(kb + 32 + k0s))*1024 + qrow0 + q0s)*16 + hp0);
        r1 = *(const f32x4*)(imb + (((size_t)(kb + 48 + k0s))*1024 + qrow0 + q0s)*16 + hp0);
      } else if (pass == 0) {
        r0 = *(const f32x4*)(imb + (((size_t)k0s)*1024 + pair*16 + q0s)*16 + hp0);
        r1 = *(const f32x4*)(imb + (((size_t)(k0s+16))*1024 + pair*16 + q0s)*16 + hp0);
      }

      // S = Q*K^T (16 q x 32 keys)
      f32x4 S[2] = {(f32x4)0.f, (f32x4)0.f};
      #pragma unroll
      for (int nt = 0; nt < 2; ++nt) {
        const u16* kp = Kb + bh + (size_t)(kb + nt*16 + c)*64 + quad*8;
        bf16x8 kf0 = *(const bf16x8*)kp;
        bf16x8 kf1 = *(const bf16x8*)(kp + 32);
        S[nt] = __builtin_amdgcn_mfma_f32_16x16x32_bf16(qf0, kf0, S[nt], 0, 0, 0);
        S[nt] = __builtin_amdgcn_mfma_f32_16x16x32_bf16(qf1, kf1, S[nt], 0, 0, 0);
      }
      // + IM; padding-mask (masked q-row == const 0 pre-softmax: -1e9+IM rounds to -1e9
      // in fp32 -> uniform attn, replicated exactly); causal
      #pragma unroll
      for (int nt = 0; nt < 2; ++nt) {
        int tk = kb + nt*16 + c;
        #pragma unroll
        for (int j = 0; j < 4; ++j) {
          float sv = S[nt][j] + lim[(nt*16 + c)*196 + (quad*4 + j)*12 + w];
          sv = rm[j] ? sv : 0.0f;
          sv = (tk <= tq[j]) ? sv : NINF;
          S[nt][j] = sv;
        }
      }
      // online softmax (rows on (quad,j); reduce across 16 c-lanes)
      float mn[4], al[4];
      #pragma unroll
      for (int j = 0; j < 4; ++j) {
        float vm = fmaxf(S[0][j], S[1][j]);
        vm = fmaxf(vm, __shfl_xor(vm, 1, 64));
        vm = fmaxf(vm, __shfl_xor(vm, 2, 64));
        vm = fmaxf(vm, __shfl_xor(vm, 4, 64));
        vm = fmaxf(vm, __shfl_xor(vm, 8, 64));
        mn[j] = fmaxf(mr[j], vm);
        al[j] = exp2f((mr[j] - mn[j]) * LOG2E);
        mr[j] = mn[j];
      }
      #pragma unroll
      for (int nt = 0; nt < 2; ++nt)
        #pragma unroll
        for (int j = 0; j < 4; ++j)
          S[nt][j] = exp2f((S[nt][j] - mn[j]) * LOG2E);
      #pragma unroll
      for (int j = 0; j < 4; ++j) {
        float sum = S[0][j] + S[1][j];
        sum += __shfl_xor(sum, 1, 64);
        sum += __shfl_xor(sum, 2, 64);
        sum += __shfl_xor(sum, 4, 64);
        sum += __shfl_xor(sum, 8, 64);
        lr[j] = lr[j]*al[j] + sum;
      }
      #pragma unroll
      for (int nd = 0; nd < 4; ++nd)
        #pragma unroll
        for (int j = 0; j < 4; ++j) O[nd][j] *= al[j];
      // P: C-layout -> A-layout via per-wave LDS (wave-ordered, no barrier)
      #pragma unroll
      for (int nt = 0; nt < 2; ++nt)
        #pragma unroll
        for (int j = 0; j < 4; ++j)
          lp[w][(quad*4 + j)*40 + nt*16 + c] = f2bf(S[nt][j]);
      bf16x8 pf = *(const bf16x8*)&lp[w][c*40 + quad*8];
      // O += P*V  (V^T: 8 contiguous keys per frag)
      #pragma unroll
      for (int nd = 0; nd < 4; ++nd) {
        bf16x8 vf = *(const bf16x8*)(VTb + bh + (size_t)(nd*16 + c)*1024 + kb + quad*8);
        O[nd] = __builtin_amdgcn_mfma_f32_16x16x32_bf16(pf, vf, O[nd], 0, 0, 0);
      }
    }

    float inv[4];
    #pragma unroll
    for (int j = 0; j < 4; ++j) inv[j] = 1.0f / lr[j];
    #pragma unroll
    for (int nd = 0; nd < 4; ++nd)
      #pragma unroll
      for (int j = 0; j < 4; ++j)
        ctx[((size_t)b*1024 + tq[j])*1024 + h*64 + nd*16 + c] = f2bf(O[nd][j] * inv[j]);
  }
}

// ---------------- launch ----------------
extern "C" void kernel_launch(void* const* d_in, const int* in_sizes, int n_in,
                              void* d_out, int out_size, void* d_ws, size_t ws_size,
                              hipStream_t stream) {
  const float* x     = (const float*)d_in[0];
  const int*   pm    = (const int*)d_in[1];
  const float* im    = (const float*)d_in[2];
  const float* wckv  = (const float*)d_in[3];
  const float* wcq   = (const float*)d_in[4];
  const float* wkc   = (const float*)d_in[5];
  const float* wqc   = (const float*)d_in[6];
  const float* wvc   = (const float*)d_in[7];
  const float* wproj = (const float*)d_in[8];
  const float* bproj = (const float*)d_in[9];
  u16* ws = (u16*)d_ws;
  float* out = (float*)d_out;

  convert_kernel<<<11264, 256, 0, stream>>>(x, wckv, wcq, wkc, wqc, wvc, wproj, ws);
  // K1: [KV|Qd] = Xbf @ [W_ckv|W_cq]   (4096x512, K=1024), 64x64 tiles, 512 blocks
  gemm_kernel<0,64,64><<<dim3(8, 64), 256, 0, stream>>>(ws + OFF_XBF, ws + OFF_WT_CKV, ws, nullptr, nullptr);
  // K2: K / Q*(1/8) / V^T  (4096x3072, K=256), 128x128 tiles, 768 blocks
  gemm_kernel<1,128,128><<<dim3(24, 32), 256, 0, stream>>>(ws + OFF_DQ, ws + OFF_WT_KC, ws, nullptr, nullptr);
  // K3: flash attention + interaction matrix (256 balanced blocks)
  attn_kernel<<<256, 512, 0, stream>>>(ws + OFF_KB, ws + OFF_QB, ws + OFF_VTB,
                                       ws + OFF_CTX, im, pm);
  // K4: out = CTX @ W_proj + b_proj (fp32), 64x128 tiles, 512 blocks
  gemm_kernel<2,64,128><<<dim3(8, 64), 256, 0, stream>>>(ws + OFF_CTX, ws + OFF_WT_PROJ, ws, out, bproj);
}

// Round 3
// 458.858 us; speedup vs baseline: 1.1467x; 1.0400x over previous
//
#include <hip/hip_runtime.h>

typedef unsigned short u16;
typedef unsigned int u32;
typedef __attribute__((ext_vector_type(8))) __bf16 bf16x8;
typedef __attribute__((ext_vector_type(4))) float f32x4;
typedef __attribute__((ext_vector_type(4))) short s16x4;
typedef __attribute__((ext_vector_type(4))) u32 u32x4;

#define LOG2E 1.4426950408889634f
#define NINF (-__builtin_inff())

// ---------------- workspace layout (u16 element offsets) ----------------
static constexpr size_t OFF_WT_CKV = 0;          // 256x1024
static constexpr size_t OFF_WT_CQ  = 262144;     // 256x1024
static constexpr size_t OFF_WT_KC  = 524288;     // 1024x256
static constexpr size_t OFF_WT_QC  = 786432;     // 1024x256
static constexpr size_t OFF_WT_VC  = 1048576;    // 1024x256
static constexpr size_t OFF_WT_PROJ= 1310720;    // 1024x1024
static constexpr size_t OFF_XBF    = 2359296;    // 4096x1024 bf16 x  (reused as CTX)
static constexpr size_t OFF_DQ     = OFF_XBF + 4194304;  // 4096x512 [KV | Qdown]
static constexpr size_t OFF_KB     = OFF_DQ  + 2097152;  // (b,h,t,d)
static constexpr size_t OFF_QB     = OFF_KB  + 4194304;  // (b,h,t,d), pre-scaled by 1/8
static constexpr size_t OFF_VTB    = OFF_QB  + 4194304;  // (b,h,d,t)
static constexpr size_t OFF_CTX    = OFF_XBF;            // alias: x dead after K1

__device__ __forceinline__ u16 f2bf(float f) {   // RNE fp32->bf16
  u32 u = __builtin_bit_cast(u32, f);
  u = (u + 0x7fffu + ((u >> 16) & 1u)) >> 16;
  return (u16)u;
}

// async global->LDS, 16B per lane. LDS dest = wave-uniform base + lane*16.
__device__ __forceinline__ void gld16(const void* g, void* l) {
  __builtin_amdgcn_global_load_lds(
      (const __attribute__((address_space(1))) u32*)(unsigned long long)g,
      (__attribute__((address_space(3))) u32*)(u32)(unsigned long long)l,
      16, 0, 0);
}

// ---------------- K0: convert x -> bf16 (x8), W -> bf16 transposed ----------------
// Transpose = gather-read (strided 4B, L2-cached: each 64B line fetched once, used 16x)
// + fully coalesced 16B/lane writes. Avoids the 2B-scatter RMW storm (64x write amp).
__device__ __forceinline__ void twrite(const float* __restrict__ w, u16* __restrict__ dst,
                                       int n, int k0, int N, int R) {
  u32x4 pv;
  #pragma unroll
  for (int jj = 0; jj < 4; ++jj) {
    u32 lo = f2bf(w[(size_t)(k0 + 2*jj) * N + n]);
    u32 hi = f2bf(w[(size_t)(k0 + 2*jj + 1) * N + n]);
    pv[jj] = lo | (hi << 16);
  }
  *(u32x4*)(dst + (size_t)n * R + k0) = pv;
}

__global__ __launch_bounds__(256) void convert_kernel(
    const float* __restrict__ xin, const float* __restrict__ w0,
    const float* __restrict__ w1, const float* __restrict__ w2,
    const float* __restrict__ w3, const float* __restrict__ w4,
    const float* __restrict__ w5, u16* __restrict__ ws) {
  int gid = blockIdx.x * 256 + threadIdx.x;
  if (gid < 524288) {                          // x: 8 elems/thread, vectorized
    int i0 = gid * 8;
    f32x4 a = *(const f32x4*)(xin + i0);
    f32x4 b = *(const f32x4*)(xin + i0 + 4);
    u32x4 pv;
    pv[0] = (u32)f2bf(a[0]) | ((u32)f2bf(a[1]) << 16);
    pv[1] = (u32)f2bf(a[2]) | ((u32)f2bf(a[3]) << 16);
    pv[2] = (u32)f2bf(b[0]) | ((u32)f2bf(b[1]) << 16);
    pv[3] = (u32)f2bf(b[2]) | ((u32)f2bf(b[3]) << 16);
    *(u32x4*)(ws + OFF_XBF + i0) = pv;
    return;
  }
  int id = gid - 524288;
  // w0/w1: R=1024 rows, N=256 cols -> 1024/8=128 k-groups/row (shift 7)
  if (id < 32768)  { int n = id >> 7, k0 = (id & 127) * 8;
    twrite(w0, ws + OFF_WT_CKV, n, k0, 256, 1024); return; }
  id -= 32768;
  if (id < 32768)  { int n = id >> 7, k0 = (id & 127) * 8;
    twrite(w1, ws + OFF_WT_CQ, n, k0, 256, 1024); return; }
  id -= 32768;
  // w2/w3/w4: R=256, N=1024 -> 32 k-groups/row (shift 5)
  if (id < 32768)  { int n = id >> 5, k0 = (id & 31) * 8;
    twrite(w2, ws + OFF_WT_KC, n, k0, 1024, 256); return; }
  id -= 32768;
  if (id < 32768)  { int n = id >> 5, k0 = (id & 31) * 8;
    twrite(w3, ws + OFF_WT_QC, n, k0, 1024, 256); return; }
  id -= 32768;
  if (id < 32768)  { int n = id >> 5, k0 = (id & 31) * 8;
    twrite(w4, ws + OFF_WT_VC, n, k0, 1024, 256); return; }
  id -= 32768;
  // w5: R=1024, N=1024 -> 128 k-groups/row (shift 7)
  if (id < 131072) { int n = id >> 7, k0 = (id & 127) * 8;
    twrite(w5, ws + OFF_WT_PROJ, n, k0, 1024, 1024); return; }
}

// ---------------- m97-style GEMM: C(4096 x N) = A(4096 x K) * BT^T ----------------
// MODE 0: K1  A=XBF lda=1024, K=1024, N=512 -> DQ bf16     (MT=64, NT=64,  grid 512)
// MODE 1: K2  A=DQ  lda=512,  K=256,  N=3072 -> K/Q/V^T    (MT=128,NT=128, grid 768)
// MODE 2: K4  A=CTX lda=1024, K=1024, N=1024 -> out + bias (MT=64, NT=128, grid 512)
template<int MODE, int MT, int NT>
__global__ __launch_bounds__(256, (MT == 128) ? 2 : 4) void gemm_kernel(
    const u16* __restrict__ A, const u16* __restrict__ BT,
    u16* __restrict__ ws, float* __restrict__ out, const float* __restrict__ bias) {
  constexpr int KDIM = (MODE == 1) ? 256 : 1024;
  constexpr int LDA  = (MODE == 1) ? 512 : 1024;
  constexpr int MW = MT / 32;
  constexpr int NW = NT / 32;
  __shared__ u16 lA[MT*32];
  __shared__ u16 lB[NT*32];
  const int t = threadIdx.x;
  const int lane = t & 63;
  const int c = lane & 15, quad = lane >> 4;
  const int w = t >> 6, wr = w >> 1, wc = w & 1;
  const int gm0 = blockIdx.y * MT, ct0 = blockIdx.x * NT;
  const u16* Ae = A;
  int out_id = 0;
  if (MODE == 1) { out_id = ct0 >> 10; if (out_id == 1) Ae += 256; }
  const int m0s = t >> 2, q0s = t & 3;

  f32x4 acc[MW][NW];
  #pragma unroll
  for (int i = 0; i < MW; ++i)
    #pragma unroll
    for (int j = 0; j < NW; ++j) acc[i][j] = (f32x4)0.0f;

  for (int k0 = 0; k0 < KDIM; k0 += 32) {
    __syncthreads();
    gld16(Ae + (size_t)(gm0 + m0s)*LDA + k0 + q0s*8, (char*)lA + t*16);
    if (MT == 128)
      gld16(Ae + (size_t)(gm0 + m0s + 64)*LDA + k0 + q0s*8, (char*)lA + (t+256)*16);
    gld16(BT + (size_t)(ct0 + m0s)*KDIM + k0 + q0s*8, (char*)lB + t*16);
    if (NT == 128)
      gld16(BT + (size_t)(ct0 + m0s + 64)*KDIM + k0 + q0s*8, (char*)lB + (t+256)*16);
    __syncthreads();
    bf16x8 af[MW], bfr[NW];
    #pragma unroll
    for (int mt = 0; mt < MW; ++mt)
      af[mt] = *(const bf16x8*)(lA + (wr*(MT/2) + mt*16 + c)*32 + quad*8);
    #pragma unroll
    for (int nt = 0; nt < NW; ++nt)
      bfr[nt] = *(const bf16x8*)(lB + (wc*(NT/2) + nt*16 + c)*32 + quad*8);
    #pragma unroll
    for (int mt = 0; mt < MW; ++mt)
      #pragma unroll
      for (int nt = 0; nt < NW; ++nt)
        acc[mt][nt] = __builtin_amdgcn_mfma_f32_16x16x32_bf16(af[mt], bfr[nt], acc[mt][nt], 0, 0, 0);
  }

  const int rbase = gm0 + wr*(MT/2);
  const int cbase = ct0 + wc*(NT/2);
  if (MODE == 0) {
    #pragma unroll
    for (int mt = 0; mt < MW; ++mt)
      #pragma unroll
      for (int nt = 0; nt < NW; ++nt)
        #pragma unroll
        for (int j = 0; j < 4; ++j) {
          int row = rbase + mt*16 + quad*4 + j;
          int col = cbase + nt*16 + c;
          ws[OFF_DQ + (size_t)row*512 + col] = f2bf(acc[mt][nt][j]);
        }
  } else if (MODE == 2) {
    float bv[NW];
    #pragma unroll
    for (int nt = 0; nt < NW; ++nt) bv[nt] = bias[cbase + nt*16 + c];
    #pragma unroll
    for (int mt = 0; mt < MW; ++mt)
      #pragma unroll
      for (int nt = 0; nt < NW; ++nt)
        #pragma unroll
        for (int j = 0; j < 4; ++j) {
          int row = rbase + mt*16 + quad*4 + j;
          out[(size_t)row*1024 + cbase + nt*16 + c] = acc[mt][nt][j] + bv[nt];
        }
  } else {
    const int cl = (ct0 & 1023) + wc*64;
    const int hcol = cl >> 6;
    if (out_id == 2) {                        // V -> (b,h,d,t)
      #pragma unroll
      for (int mt = 0; mt < MW; ++mt) {
        int row0 = rbase + mt*16 + quad*4;
        int bb = row0 >> 10, t0 = row0 & 1023;
        #pragma unroll
        for (int nt = 0; nt < NW; ++nt) {
          int d = nt*16 + c;
          s16x4 pk;
          #pragma unroll
          for (int j = 0; j < 4; ++j) pk[j] = (short)f2bf(acc[mt][nt][j]);
          *(s16x4*)(ws + OFF_VTB + (((size_t)bb*16 + hcol)*64 + d)*1024 + t0) = pk;
        }
      }
    } else {                                  // K / Q(*1/8) -> (b,h,t,d)
      const float sc = out_id ? 0.125f : 1.0f;
      const size_t base = out_id ? OFF_QB : OFF_KB;
      #pragma unroll
      for (int mt = 0; mt < MW; ++mt)
        #pragma unroll
        for (int nt = 0; nt < NW; ++nt)
          #pragma unroll
          for (int j = 0; j < 4; ++j) {
            int row = rbase + mt*16 + quad*4 + j;
            int bb = row >> 10, tt = row & 1023;
            ws[base + ((((size_t)bb*16 + hcol)*1024 + tt)<<6) + nt*16 + c]
                = f2bf(acc[mt][nt][j]*sc);
          }
    }
  }
}

// ---------------- K3: flash attention + fused interaction-matrix ----------------
// 256 blocks x 512 thr (8 waves = 8 heads); block covers q-tiles qtA=63-pair, qtB=pair
// flattened into ONE 33-tile pipeline (perfect balance, never drains at the pass seam).
// Per tile: prefetch next tile's IM (regs), K-frags, V-frags during compute; IM LDS is
// double-buffered -> ONE barrier per tile. hh-siblings (bi, bi+8) land on the same XCD
// (bi%8) so each 64B IM line is fetched once into that XCD's L2, halves consumed by the
// two siblings. IM stream is the BW floor (~135 MB -> ~21 us).
__global__ __launch_bounds__(512, 2) void attn_kernel(
    const u16* __restrict__ Kb, const u16* __restrict__ Qb,
    const u16* __restrict__ VTb, u16* __restrict__ ctx,
    const float* __restrict__ im, const int* __restrict__ pmask) {
  __shared__ float lim[2][32*196];     // k-stride 196, q-stride 12 dwords (<=4-way bk)
  __shared__ u16   lp[8][16*40];       // per-wave P transform (C-layout -> A-layout)

  const int t = threadIdx.x, lane = t & 63, w = t >> 6;
  const int c = lane & 15, quad = lane >> 4;
  const int bi = blockIdx.x;
  const int g = bi >> 4, hh = (bi >> 3) & 1, s = bi & 7;
  const int b = s >> 1, pair = g*2 + (s & 1);
  const int h = hh*8 + w;
  const size_t bh = ((size_t)b*16 + h) << 16;
  const int qtA = 63 - pair, qtB = pair;
  const int ntA = ((qtA*16 + 15) >> 5) + 1;   // tiles in pass A (ntA + ntB == 33)

  // IM staging decode: thread -> (k, q, h-quad) chunk, 16B each
  const int k0s = t >> 5, q0s = (t & 31) >> 1, hp0 = (t & 1) * 4;
  const float* imb = im + ((size_t)b << 24) + hh*8;
  const int loff0 = k0s*196 + q0s*12 + hp0;
  const int loff1 = (k0s + 16)*196 + q0s*12 + hp0;

  // ---- per-pass state (pass A first) ----
  int qrow = qtA * 16;
  bf16x8 qf0 = *(const bf16x8*)(Qb + bh + (size_t)(qrow + c)*64 + quad*8);
  bf16x8 qf1 = *(const bf16x8*)(Qb + bh + (size_t)(qrow + c)*64 + 32 + quad*8);
  int tq[4], rm[4];
  #pragma unroll
  for (int j = 0; j < 4; ++j) {
    tq[j] = qrow + quad*4 + j;
    rm[j] = pmask[b*1024 + tq[j]];
  }
  float mr[4] = {NINF, NINF, NINF, NINF};
  float lr[4] = {0.f, 0.f, 0.f, 0.f};
  f32x4 O[4] = {(f32x4)0.f, (f32x4)0.f, (f32x4)0.f, (f32x4)0.f};

  // ---- prologue: tile 0 (kb=0, pass A) ----
  f32x4 r0 = *(const f32x4*)(imb + ((size_t)k0s*1024 + qrow + q0s)*16 + hp0);
  f32x4 r1 = *(const f32x4*)(imb + ((size_t)(k0s+16)*1024 + qrow + q0s)*16 + hp0);
  bf16x8 kc00 = *(const bf16x8*)(Kb + bh + (size_t)(c)*64 + quad*8);
  bf16x8 kc01 = *(const bf16x8*)(Kb + bh + (size_t)(c)*64 + 32 + quad*8);
  bf16x8 kc10 = *(const bf16x8*)(Kb + bh + (size_t)(16 + c)*64 + quad*8);
  bf16x8 kc11 = *(const bf16x8*)(Kb + bh + (size_t)(16 + c)*64 + 32 + quad*8);
  bf16x8 vc[4];
  #pragma unroll
  for (int nd = 0; nd < 4; ++nd)
    vc[nd] = *(const bf16x8*)(VTb + bh + (size_t)(nd*16 + c)*1024 + quad*8);
  *(f32x4*)(&lim[0][loff0]) = r0;
  *(f32x4*)(&lim[0][loff1]) = r1;
  __syncthreads();

  for (int i = 0; i < 33; ++i) {
    const int cb = i & 1;
    const int kb = (i < ntA ? i : i - ntA) * 32;
    const int ip = i + 1;
    const bool havep = ip < 33;

    // ---- prefetch tile ip (IM -> regs, K/V -> frag regs) ----
    bf16x8 kn00, kn01, kn10, kn11, vn[4];
    if (havep) {
      const int kbp = (ip < ntA ? ip : ip - ntA) * 32;
      const int qrp = (ip < ntA ? qtA : qtB) * 16;
      r0 = *(const f32x4*)(imb + ((size_t)(kbp + k0s)*1024 + qrp + q0s)*16 + hp0);
      r1 = *(const f32x4*)(imb + ((size_t)(kbp + 16 + k0s)*1024 + qrp + q0s)*16 + hp0);
      const u16* kp = Kb + bh + (size_t)(kbp + c)*64 + quad*8;
      kn00 = *(const bf16x8*)kp;
      kn01 = *(const bf16x8*)(kp + 32);
      kn10 = *(const bf16x8*)(kp + 1024);
      kn11 = *(const bf16x8*)(kp + 1056);
      #pragma unroll
      for (int nd = 0; nd < 4; ++nd)
        vn[nd] = *(const bf16x8*)(VTb + bh + (size_t)(nd*16 + c)*1024 + kbp + quad*8);
    }

    // ---- S = Q*K^T (16q x 32 keys) ----
    f32x4 S[2] = {(f32x4)0.f, (f32x4)0.f};
    S[0] = __builtin_amdgcn_mfma_f32_16x16x32_bf16(qf0, kc00, S[0], 0, 0, 0);
    S[0] = __builtin_amdgcn_mfma_f32_16x16x32_bf16(qf1, kc01, S[0], 0, 0, 0);
    S[1] = __builtin_amdgcn_mfma_f32_16x16x32_bf16(qf0, kc10, S[1], 0, 0, 0);
    S[1] = __builtin_amdgcn_mfma_f32_16x16x32_bf16(qf1, kc11, S[1], 0, 0, 0);

    // + IM; padding-mask (masked q-row == const 0 pre-softmax: -1e9+IM rounds to -1e9
    // in fp32 -> uniform attn, replicated exactly); causal
    #pragma unroll
    for (int nt = 0; nt < 2; ++nt) {
      int tk = kb + nt*16 + c;
      #pragma unroll
      for (int j = 0; j < 4; ++j) {
        float sv = S[nt][j] + lim[cb][(nt*16 + c)*196 + (quad*4 + j)*12 + w];
        sv = rm[j] ? sv : 0.0f;
        sv = (tk <= tq[j]) ? sv : NINF;
        S[nt][j] = sv;
      }
    }
    // ---- online softmax (rows on (quad,j); reduce across 16 c-lanes) ----
    float mn[4], al[4];
    #pragma unroll
    for (int j = 0; j < 4; ++j) {
      float vm = fmaxf(S[0][j], S[1][j]);
      vm = fmaxf(vm, __shfl_xor(vm, 1, 64));
      vm = fmaxf(vm, __shfl_xor(vm, 2, 64));
      vm = fmaxf(vm, __shfl_xor(vm, 4, 64));
      vm = fmaxf(vm, __shfl_xor(vm, 8, 64));
      mn[j] = fmaxf(mr[j], vm);
      al[j] = exp2f((mr[j] - mn[j]) * LOG2E);
      mr[j] = mn[j];
    }
    #pragma unroll
    for (int nt = 0; nt < 2; ++nt)
      #pragma unroll
      for (int j = 0; j < 4; ++j)
        S[nt][j] = exp2f((S[nt][j] - mn[j]) * LOG2E);
    #pragma unroll
    for (int j = 0; j < 4; ++j) {
      float sum = S[0][j] + S[1][j];
      sum += __shfl_xor(sum, 1, 64);
      sum += __shfl_xor(sum, 2, 64);
      sum += __shfl_xor(sum, 4, 64);
      sum += __shfl_xor(sum, 8, 64);
      lr[j] = lr[j]*al[j] + sum;
    }
    #pragma unroll
    for (int nd = 0; nd < 4; ++nd)
      #pragma unroll
      for (int j = 0; j < 4; ++j) O[nd][j] *= al[j];
    // P: C-layout -> A-layout via per-wave LDS (wave-ordered DS, no barrier)
    #pragma unroll
    for (int nt = 0; nt < 2; ++nt)
      #pragma unroll
      for (int j = 0; j < 4; ++j)
        lp[w][(quad*4 + j)*40 + nt*16 + c] = f2bf(S[nt][j]);
    bf16x8 pf = *(const bf16x8*)&lp[w][c*40 + quad*8];
    #pragma unroll
    for (int nd = 0; nd < 4; ++nd)
      O[nd] = __builtin_amdgcn_mfma_f32_16x16x32_bf16(pf, vc[nd], O[nd], 0, 0, 0);

    // ---- stage next IM tile into the other buffer; single barrier ----
    if (havep) {
      *(f32x4*)(&lim[cb ^ 1][loff0]) = r0;
      *(f32x4*)(&lim[cb ^ 1][loff1]) = r1;
    }
    __syncthreads();
    if (havep) {
      kc00 = kn00; kc01 = kn01; kc10 = kn10; kc11 = kn11;
      #pragma unroll
      for (int nd = 0; nd < 4; ++nd) vc[nd] = vn[nd];
    }

    // ---- pass seam: flush pass-A output, reset state for pass B ----
    if (i == ntA - 1) {
      float inv[4];
      #pragma unroll
      for (int j = 0; j < 4; ++j) inv[j] = 1.0f / lr[j];
      #pragma unroll
      for (int nd = 0; nd < 4; ++nd)
        #pragma unroll
        for (int j = 0; j < 4; ++j)
          ctx[((size_t)b*1024 + tq[j])*1024 + h*64 + nd*16 + c] = f2bf(O[nd][j]*inv[j]);
      qrow = qtB * 16;
      qf0 = *(const bf16x8*)(Qb + bh + (size_t)(qrow + c)*64 + quad*8);
      qf1 = *(const bf16x8*)(Qb + bh + (size_t)(qrow + c)*64 + 32 + quad*8);
      #pragma unroll
      for (int j = 0; j < 4; ++j) {
        tq[j] = qrow + quad*4 + j;
        rm[j] = pmask[b*1024 + tq[j]];
        mr[j] = NINF; lr[j] = 0.f;
        O[j] = (f32x4)0.f;
      }
    }
  }

  float inv[4];
  #pragma unroll
  for (int j = 0; j < 4; ++j) inv[j] = 1.0f / lr[j];
  #pragma unroll
  for (int nd = 0; nd < 4; ++nd)
    #pragma unroll
    for (int j = 0; j < 4; ++j)
      ctx[((size_t)b*1024 + tq[j])*1024 + h*64 + nd*16 + c] = f2bf(O[nd][j]*inv[j]);
}

// ---------------- launch ----------------
extern "C" void kernel_launch(void* const* d_in, const int* in_sizes, int n_in,
                              void* d_out, int out_size, void* d_ws, size_t ws_size,
                              hipStream_t stream) {
  const float* x     = (const float*)d_in[0];
  const int*   pm    = (const int*)d_in[1];
  const float* im    = (const float*)d_in[2];
  const float* wckv  = (const float*)d_in[3];
  const float* wcq   = (const float*)d_in[4];
  const float* wkc   = (const float*)d_in[5];
  const float* wqc   = (const float*)d_in[6];
  const float* wvc   = (const float*)d_in[7];
  const float* wproj = (const float*)d_in[8];
  const float* bproj = (const float*)d_in[9];
  u16* ws = (u16*)d_ws;
  float* out = (float*)d_out;

  convert_kernel<<<3200, 256, 0, stream>>>(x, wckv, wcq, wkc, wqc, wvc, wproj, ws);
  // K1: [KV|Qd] = Xbf @ [W_ckv|W_cq]   (4096x512, K=1024), 64x64 tiles
  gemm_kernel<0,64,64><<<dim3(8, 64), 256, 0, stream>>>(ws + OFF_XBF, ws + OFF_WT_CKV, ws, nullptr, nullptr);
  // K2: K / Q*(1/8) / V^T  (4096x3072, K=256), 128x128 tiles
  gemm_kernel<1,128,128><<<dim3(24, 32), 256, 0, stream>>>(ws + OFF_DQ, ws + OFF_WT_KC, ws, nullptr, nullptr);
  // K3: flash attention + interaction matrix (256 balanced blocks, 1-deep pipeline)
  attn_kernel<<<256, 512, 0, stream>>>(ws + OFF_KB, ws + OFF_QB, ws + OFF_VTB,
                                       ws + OFF_CTX, im, pm);
  // K4: out = CTX @ W_proj + b_proj (fp32), 64x128 tiles
  gemm_kernel<2,64,128><<<dim3(8, 64), 256, 0, stream>>>(ws + OFF_CTX, ws + OFF_WT_PROJ, ws, out, bproj);
}